// Round 12
// baseline (340.532 us; speedup 1.0000x reference)
//
#include <hip/hip_runtime.h>
#include <cmath>

typedef _Float16 f16;
typedef _Float16 f16x4 __attribute__((ext_vector_type(4)));
typedef _Float16 f16x8 __attribute__((ext_vector_type(8)));
typedef float f32x4 __attribute__((ext_vector_type(4)));
typedef unsigned int u32x2 __attribute__((ext_vector_type(2)));
typedef unsigned int u32x4 __attribute__((ext_vector_type(4)));

#define B 64
#define S 80
#define KC 32
#define EDIM 256
#define HDIM 512
#define G3 1536
#define LDIM 128

// persistent-GRU geometry: 8 groups x 8 blocks x 64 cols, gates in-wave
#define NG 8     // groups (grid(8,8): linear%8 == g -> one XCD per group)
#define PG 8     // patients per group
#define NJ 8     // blocks per group (fan-in 8)
#define CPB 64   // h-cols per block

// sync area layout (u32 units)
#define OFF_PCNT  (NG * NJ * 64)
#define OFF_XCD   (OFF_PCNT + NG * 64)
#define OFF_TEST  (OFF_XCD + NG * NJ)
#define OFF_FAIL  (OFF_TEST + NG * NJ * 64)
#define SYNC_TOTAL (OFF_FAIL + NG)

// ---------------------------------------------------------------------------
__device__ __forceinline__ unsigned int ld_u32c(const unsigned int* p, bool l2) {
    unsigned int v;
    if (l2) {
        asm volatile("global_load_dword %0, %1, off sc0\n\ts_waitcnt vmcnt(0)"
                     : "=v"(v) : "v"(p) : "memory");
    } else {
        v = __hip_atomic_load(p, __ATOMIC_RELAXED, __HIP_MEMORY_SCOPE_AGENT);
    }
    return v;
}
__device__ __forceinline__ void st_u32c(unsigned int* p, unsigned int v, bool l2) {
    if (l2) {
        asm volatile("global_store_dword %0, %1, off sc0" :: "v"(p), "v"(v) : "memory");
    } else {
        __hip_atomic_store(p, v, __ATOMIC_RELAXED, __HIP_MEMORY_SCOPE_AGENT);
    }
}

// ---------------------------------------------------------------------------
// K1: multi-hot embedding + tanh -> f16.
__global__ __launch_bounds__(256) void emb_kernel(const int* __restrict__ seq,
                                                  const float* __restrict__ Ew,
                                                  unsigned short* __restrict__ emb16) {
    int bs = blockIdx.x;
    __shared__ int codes[KC];
    __shared__ int valid[KC];
    int tid = threadIdx.x;
    if (tid < KC) codes[tid] = seq[bs * KC + tid];
    __syncthreads();
    if (tid < KC) {
        int c = codes[tid];
        int v = (c != 0);
        for (int i = 0; i < tid; ++i)
            if (codes[i] == c) v = 0;
        valid[tid] = v;
    }
    __syncthreads();
    float acc = 0.f;
    for (int j = 0; j < KC; ++j) {
        if (valid[j]) acc += Ew[codes[j] * EDIM + tid];
    }
    emb16[bs * EDIM + tid] = __builtin_bit_cast(unsigned short, (f16)tanhf(acc));
}

// ---------------------------------------------------------------------------
// K2: Gi16 = emb16 @ Wi16^T + bi via MFMA f16 (verified).
__global__ __launch_bounds__(256) void gi_gemm16(
        const unsigned short* __restrict__ wi16,
        const unsigned short* __restrict__ emb16,
        const float* __restrict__ bi,
        unsigned short* __restrict__ gi16) {
    __shared__ __align__(16) f16 At[64][256];
    __shared__ __align__(16) f16 Bt[64][256];
    const int m0 = blockIdx.x * 64;   // visits
    const int n0 = blockIdx.y * 64;   // gates
    const int tid = threadIdx.x;
    #pragma unroll
    for (int i = 0; i < 8; ++i) {
        int ci = tid + i * 256;
        int row = ci >> 5, c = ci & 31;
        int sc = c ^ (row & 7);
        *(f32x4*)&At[row][sc * 8] =
            *(const f32x4*)(wi16 + (size_t)(n0 + row) * EDIM + c * 8);
        *(f32x4*)&Bt[row][sc * 8] =
            *(const f32x4*)(emb16 + (size_t)(m0 + row) * EDIM + c * 8);
    }
    __syncthreads();
    const int wv = tid >> 6, ln = tid & 63;
    const int lr = ln & 15, hi = ln >> 4;
    const int arow = wv * 16 + lr;
    f32x4 acc[4] = {};
    #pragma unroll
    for (int ks = 0; ks < 8; ++ks) {
        int ca = (ks * 4 + hi) ^ (arow & 7);
        f32x4 av = *(const f32x4*)&At[arow][ca * 8];
        #pragma unroll
        for (int vt = 0; vt < 4; ++vt) {
            int brow = vt * 16 + lr;
            int cb = (ks * 4 + hi) ^ (brow & 7);
            f32x4 bv = *(const f32x4*)&Bt[brow][cb * 8];
            acc[vt] = __builtin_amdgcn_mfma_f32_16x16x32_f16(
                __builtin_bit_cast(f16x8, av), __builtin_bit_cast(f16x8, bv),
                acc[vt], 0, 0, 0);
        }
    }
    const int gate0 = n0 + wv * 16 + hi * 4;
    float4 bv4 = *(const float4*)(bi + gate0);
    #pragma unroll
    for (int vt = 0; vt < 4; ++vt) {
        int vis = m0 + vt * 16 + lr;
        union { unsigned short u[4]; unsigned long long ll; } pk;
        pk.u[0] = __builtin_bit_cast(unsigned short, (f16)(acc[vt][0] + bv4.x));
        pk.u[1] = __builtin_bit_cast(unsigned short, (f16)(acc[vt][1] + bv4.y));
        pk.u[2] = __builtin_bit_cast(unsigned short, (f16)(acc[vt][2] + bv4.z));
        pk.u[3] = __builtin_bit_cast(unsigned short, (f16)(acc[vt][3] + bv4.w));
        *(unsigned long long*)(gi16 + (size_t)vis * G3 + gate0) = pk.ll;
    }
}

// ---------------------------------------------------------------------------
// K3: init — zero h buffers + sync, convert Wi/Wh -> f16, rank.
__global__ __launch_bounds__(256) void init_kernel(const int* __restrict__ len,
                                                   const float* __restrict__ Wi,
                                                   const float* __restrict__ Wh,
                                                   int* __restrict__ rank,
                                                   unsigned int* __restrict__ sync,
                                                   unsigned int* __restrict__ hz,
                                                   unsigned short* __restrict__ wi16,
                                                   unsigned short* __restrict__ wh16) {
    int idx = blockIdx.x * 256 + threadIdx.x;       // 128*256 = 32768
    if (idx < 16384) { hz[idx] = 0u; hz[16384 + idx] = 0u; }   // h0f+h1f
    for (int o = idx; o < SYNC_TOTAL; o += 32768) sync[o] = 0u;
    for (int o = idx; o < G3 * EDIM; o += 32768)
        wi16[o] = __builtin_bit_cast(unsigned short, (f16)Wi[o]);
    for (int o = idx; o < G3 * HDIM; o += 32768)
        wh16[o] = __builtin_bit_cast(unsigned short, (f16)Wh[o]);
    if (blockIdx.x == 0 && threadIdx.x < B) {
        int t = threadIdx.x;
        int lb = len[t];
        int r = 0;
        for (int i = 0; i < B; ++i) {
            int li = len[i];
            r += (li > lb) || (li == lb && i < t);
        }
        rank[t] = r;
    }
}

// ---------------------------------------------------------------------------
// K4: persistent MFMA GRU.  grid(8,8): block = 64 cols x 8 patients; each
// wave owns 16 cols and computes ALL 3 gates (D[row=col][col=pat] -> the
// three gate sums for a (col,pat) land in the SAME lane: gates in-register,
// no cross-wave LDS).  Wh fragments af[3][16] = 192 VGPR/thread, kept
// loop-resident by an IN-LOOP asm pin (loop-carried through opaque asm ->
// not rematerializable; R3-R11 all failed by pinning only at init).
// Fan-in 8 flag barrier; sc0/XCD-L2 when probed, L3 relaxed fallback.
__global__ __launch_bounds__(256, 1) void gru_persist(
        const unsigned short* __restrict__ gi16,
        const unsigned short* __restrict__ wh16,
        const float* __restrict__ bh, const int* __restrict__ len,
        unsigned short* __restrict__ h0f, unsigned short* __restrict__ h1f,
        unsigned short* __restrict__ hout,
        unsigned int* __restrict__ sync) {
    const int g     = blockIdx.x;          // 0..7 (XCD under %8 map)
    const int slice = blockIdx.y;          // 0..7
    const int tid   = threadIdx.x;
    const int wv    = tid >> 6;
    const int ln    = tid & 63;
    const int c0    = slice * CPB;

    __shared__ __align__(16) f16 hsb[64][17][8];   // [k8][pat(8real+8pad+1)][8]
    __shared__ unsigned int ids_sh[NJ];
    __shared__ unsigned int fail_sh;

    // zero pad-patient rows once (stay zero)
    for (int c = tid; c < 64 * 8; c += 256)
        *(float4*)&hsb[c >> 3][8 + (c & 7)][0] = make_float4(0.f, 0.f, 0.f, 0.f);

    // ---- per-lane geometry
    const int pat   = ln & 15;             // A-row / B-col lane field
    const int cq    = ln >> 4;             // 0..3
    const int cbase = c0 + wv * 16 + cq * 4;   // 4 output cols per lane
    const bool act  = (pat < 8);
    const int fb    = g * PG + (pat & 7);

    // ---- Wh fragments: af[gate][ks] (192 VGPR), loaded once
    f32x4 af[3][16];
    #pragma unroll
    for (int gg = 0; gg < 3; ++gg) {
        const unsigned short* wrow =
            wh16 + (size_t)(gg * HDIM + c0 + wv * 16 + pat) * HDIM + cq * 8;
        #pragma unroll
        for (int ks = 0; ks < 16; ++ks)
            af[gg][ks] = *(const f32x4*)(wrow + ks * 32);
    }

    // ---- sync pointers
    unsigned int* gflags = sync + (size_t)(g * NJ) * 64;
    unsigned int* pcnt   = sync + OFF_PCNT + g * 64;
    unsigned int* xcdrow = sync + OFF_XCD + g * NJ;
    unsigned int* town   = sync + OFF_TEST + (g * NJ + slice) * 64;
    unsigned int* tpeer  = sync + OFF_TEST + (g * NJ + ((slice + 1) & (NJ - 1))) * 64;
    unsigned int* failw  = sync + OFF_FAIL + g;

    auto l3bar = [&](unsigned int target) {
        if (tid == 0) {
            asm volatile("s_waitcnt vmcnt(0)" ::: "memory");
            __hip_atomic_fetch_add(pcnt, 1u, __ATOMIC_RELAXED, __HIP_MEMORY_SCOPE_AGENT);
            while (__hip_atomic_load(pcnt, __ATOMIC_RELAXED, __HIP_MEMORY_SCOPE_AGENT) < target)
                __builtin_amdgcn_s_sleep(1);
        }
        __syncthreads();
    };

    // ---- XCD identity + sc0 coherence probe (R6 recipe, proven)
    unsigned int myxcc;
    asm volatile("s_getreg_b32 %0, hwreg(HW_REG_XCC_ID)" : "=s"(myxcc));
    myxcc &= 0xFu;
    if (tid == 0)
        __hip_atomic_store(xcdrow + slice, myxcc, __ATOMIC_RELAXED, __HIP_MEMORY_SCOPE_AGENT);
    l3bar(NJ);
    if (tid < NJ)
        ids_sh[tid] = __hip_atomic_load(xcdrow + tid, __ATOMIC_RELAXED, __HIP_MEMORY_SCOPE_AGENT);
    __syncthreads();
    bool same_xcd = true;
    #pragma unroll
    for (int i = 1; i < NJ; ++i) same_xcd &= (ids_sh[i] == ids_sh[0]);

    bool l2m = false;
    if (same_xcd) {
        const unsigned int M1 = 0xA5A50000u + (unsigned)slice;
        const unsigned int M2 = 0x5A5A0000u + (unsigned)slice;
        const unsigned int P1 = 0xA5A50000u + (unsigned)((slice + 1) & (NJ - 1));
        const unsigned int P2 = 0x5A5A0000u + (unsigned)((slice + 1) & (NJ - 1));
        unsigned int r1 = 0, r2 = 0;
        if (tid == 0) st_u32c(town, M1, true);
        l3bar(2 * NJ);
        if (tid == 0) r1 = ld_u32c(tpeer, true);
        l3bar(3 * NJ);
        if (tid == 0) st_u32c(town, M2, true);
        l3bar(4 * NJ);
        if (tid == 0) {
            r2 = ld_u32c(tpeer, true);
            if (r1 != P1 || r2 != P2)
                __hip_atomic_fetch_or(failw, 1u, __ATOMIC_RELAXED, __HIP_MEMORY_SCOPE_AGENT);
        }
        l3bar(5 * NJ);
        if (tid == 0)
            fail_sh = __hip_atomic_load(failw, __ATOMIC_RELAXED, __HIP_MEMORY_SCOPE_AGENT);
        __syncthreads();
        l2m = (fail_sh == 0u);
    }

    // ---- per-lane statics
    float4 bhv[3] = {};
    const unsigned short* gi_b = gi16;
    int flen = 0;
    if (act) {
        #pragma unroll
        for (int gg = 0; gg < 3; ++gg)
            bhv[gg] = *(const float4*)(bh + gg * HDIM + cbase);
        gi_b = gi16 + (size_t)fb * S * G3;
        flen = len[fb];
    }
    int Lg = 0;
    #pragma unroll
    for (int i = 0; i < PG; ++i) Lg = max(Lg, len[g * PG + i]);

    unsigned short* hb0 = h0f + (size_t)g * PG * HDIM;
    unsigned short* hb1 = h1f + (size_t)g * PG * HDIM;

    // gather chunks: c = tid, tid+256 -> pat = c&7, k8 = c>>3
    const int g0p = tid & 7, g0k = tid >> 3;   // k8 0..31
    const int g1k = g0k + 32;                  // k8 32..63

    // ---- Gi(0) prologue prefetch (3 x f16x4)
    f16x4 giC[3] = {};
    if (act) {
        #pragma unroll
        for (int gg = 0; gg < 3; ++gg)
            giC[gg] = *(const f16x4*)(gi_b + gg * HDIM + cbase);
    }

    f16x4 lastH = {};

    #pragma unroll 1
    for (int t = 0; t < Lg; ++t) {
        // ---- LOOP-CARRIED PIN: af cannot be rematerialized across this
        #pragma unroll
        for (int gg = 0; gg < 3; ++gg)
            #pragma unroll
            for (int ks = 0; ks < 16; ++ks)
                asm volatile("" : "+v"(af[gg][ks]));

        const unsigned short* src = (t & 1) ? hb1 : hb0;
        unsigned short*       dst = (t & 1) ? hb0 : hb1;

        // ---- gather h_t (8 pats x 512) into LDS
        {
            const unsigned short* p0 = src + g0p * HDIM + g0k * 8;
            const unsigned short* p1 = src + g0p * HDIM + g1k * 8;
            if (l2m) {
                u32x4 v0, v1;
                asm volatile(
                    "global_load_dwordx4 %0, %2, off sc0\n\t"
                    "global_load_dwordx4 %1, %3, off sc0\n\t"
                    "s_waitcnt vmcnt(0)"
                    : "=v"(v0), "=v"(v1) : "v"(p0), "v"(p1) : "memory");
                *(u32x4*)&hsb[g0k][g0p][0] = v0;
                *(u32x4*)&hsb[g1k][g0p][0] = v1;
            } else {
                u32x4 v0, v1;
                #pragma unroll
                for (int i = 0; i < 4; ++i) {
                    v0[i] = __hip_atomic_load((const unsigned int*)p0 + i,
                                              __ATOMIC_RELAXED, __HIP_MEMORY_SCOPE_AGENT);
                    v1[i] = __hip_atomic_load((const unsigned int*)p1 + i,
                                              __ATOMIC_RELAXED, __HIP_MEMORY_SCOPE_AGENT);
                }
                *(u32x4*)&hsb[g0k][g0p][0] = v0;
                *(u32x4*)&hsb[g1k][g0p][0] = v1;
            }
        }
        __syncthreads();

        // ---- MFMA: this wave's 16 cols, all 3 gates, 2x8 K-chains each
        f32x4 s0[3], s1[3];
        #pragma unroll
        for (int gg = 0; gg < 3; ++gg) {
            s0[gg] = (f32x4){0.f, 0.f, 0.f, 0.f};
            s1[gg] = (f32x4){0.f, 0.f, 0.f, 0.f};
        }
        #pragma unroll
        for (int ks = 0; ks < 8; ++ks) {
            f32x4 bv = *(const f32x4*)&hsb[ks * 4 + cq][pat][0];
            #pragma unroll
            for (int gg = 0; gg < 3; ++gg)
                s0[gg] = __builtin_amdgcn_mfma_f32_16x16x32_f16(
                    __builtin_bit_cast(f16x8, af[gg][ks]),
                    __builtin_bit_cast(f16x8, bv), s0[gg], 0, 0, 0);
        }
        #pragma unroll
        for (int ks = 8; ks < 16; ++ks) {
            f32x4 bv = *(const f32x4*)&hsb[ks * 4 + cq][pat][0];
            #pragma unroll
            for (int gg = 0; gg < 3; ++gg)
                s1[gg] = __builtin_amdgcn_mfma_f32_16x16x32_f16(
                    __builtin_bit_cast(f16x8, af[gg][ks]),
                    __builtin_bit_cast(f16x8, bv), s1[gg], 0, 0, 0);
        }

        // ---- gates in-register (lane owns (pat, cbase..cbase+3))
        if (act) {
            f16x4 holdv = *(const f16x4*)&hsb[cbase >> 3][pat][cbase & 7];
            union { f16 h[4]; u32x2 v; } pk;
            #pragma unroll
            for (int i = 0; i < 4; ++i) {
                float sr = s0[0][i] + s1[0][i];
                float sz = s0[1][i] + s1[1][i];
                float sn = s0[2][i] + s1[2][i];
                float gr = (float)giC[0][i], gz = (float)giC[1][i],
                      gn = (float)giC[2][i];
                float bb = (i == 0) ? bhv[0].x : (i == 1) ? bhv[0].y
                         : (i == 2) ? bhv[0].z : bhv[0].w;
                float bz = (i == 0) ? bhv[1].x : (i == 1) ? bhv[1].y
                         : (i == 2) ? bhv[1].z : bhv[1].w;
                float bn = (i == 0) ? bhv[2].x : (i == 1) ? bhv[2].y
                         : (i == 2) ? bhv[2].z : bhv[2].w;
                float r  = 1.f / (1.f + expf(-(gr + sr + bb)));
                float z  = 1.f / (1.f + expf(-(gz + sz + bz)));
                float nn = tanhf(gn + r * (sn + bn));
                float hold = (float)holdv[i];
                float hnew = (t < flen) ? ((1.f - z) * nn + z * hold) : hold;
                pk.h[i] = (f16)hnew;
            }
            lastH = *(f16x4*)&pk.h[0];
            unsigned short* d = dst + pat * HDIM + cbase;
            if (l2m) {
                asm volatile("global_store_dwordx2 %0, %1, off sc0"
                             :: "v"(d), "v"(pk.v) : "memory");
            } else {
                __hip_atomic_store((unsigned int*)d, pk.v[0],
                                   __ATOMIC_RELAXED, __HIP_MEMORY_SCOPE_AGENT);
                __hip_atomic_store((unsigned int*)d + 1, pk.v[1],
                                   __ATOMIC_RELAXED, __HIP_MEMORY_SCOPE_AGENT);
            }
        }
        // drain every wave's h-stores, then cross-wave barrier, THEN flag
        asm volatile("s_waitcnt vmcnt(0)" ::: "memory");
        __syncthreads();
        if (tid == 0) st_u32c(gflags + slice * 64, (unsigned)(t + 1), l2m);

        // ---- Gi(t+1) prefetch AFTER flag publish (overlaps the poll)
        f16x4 giN[3] = {};
        if (act) {
            int tn = (t + 1 < S) ? (t + 1) : (S - 1);
            const unsigned short* gp = gi_b + (size_t)tn * G3;
            #pragma unroll
            for (int gg = 0; gg < 3; ++gg)
                giN[gg] = *(const f16x4*)(gp + gg * HDIM + cbase);
        }

        // ---- parallel poll for all 8 peers at step t+1
        if (tid < NJ) {
            unsigned int* f = gflags + tid * 64;
            while (ld_u32c(f, l2m) < (unsigned)(t + 1))
                __builtin_amdgcn_s_sleep(1);
        }
        __syncthreads();

        giC[0] = giN[0]; giC[1] = giN[1]; giC[2] = giN[2];
    }

    // ---- final h -> hout (lane owns (pat, cbase..+3))
    if (act) {
        union { f16 h[4]; u32x2 v; } pk;
        *(f16x4*)&pk.h[0] = lastH;
        *(u32x2*)(hout + (size_t)fb * HDIM + cbase) = pk.v;
    }
}

// ---------------------------------------------------------------------------
// K5: out[rank[b]] = tanh(W_lat @ h[b] + b_lat), h f16.
__global__ __launch_bounds__(128) void final_kernel(const unsigned short* __restrict__ h,
                                                    const float* __restrict__ Wl,
                                                    const float* __restrict__ bl,
                                                    const int* __restrict__ rank,
                                                    float* __restrict__ out) {
    int b = blockIdx.x;
    int l = threadIdx.x;
    __shared__ float hsh[HDIM];
    for (int i = l; i < HDIM; i += LDIM)
        hsh[i] = (float)__builtin_bit_cast(f16, h[(size_t)b * HDIM + i]);
    __syncthreads();
    float acc = bl[l];
    for (int k = 0; k < HDIM; ++k) acc += hsh[k] * Wl[(size_t)l * HDIM + k];
    out[(size_t)rank[b] * LDIM + l] = tanhf(acc);
}

// ---------------------------------------------------------------------------
extern "C" void kernel_launch(void* const* d_in, const int* in_sizes, int n_in,
                              void* d_out, int out_size, void* d_ws, size_t ws_size,
                              hipStream_t stream) {
    const int*   seq = (const int*)d_in[0];
    const int*   len = (const int*)d_in[1];
    const float* Ew  = (const float*)d_in[2];
    const float* Wi  = (const float*)d_in[3];
    const float* Wh  = (const float*)d_in[4];
    const float* bi  = (const float*)d_in[5];
    const float* bh  = (const float*)d_in[6];
    const float* Wl  = (const float*)d_in[7];
    const float* bl  = (const float*)d_in[8];
    float* out = (float*)d_out;

    unsigned short* ws16 = (unsigned short*)d_ws;
    unsigned short* emb16 = ws16;                               // B*S*E
    unsigned short* gi16  = emb16 + (size_t)B * S * EDIM;       // B*S*3H
    unsigned short* wi16  = gi16 + (size_t)B * S * G3;          // 3H*E
    unsigned short* wh16  = wi16 + (size_t)G3 * EDIM;           // 3H*H
    unsigned short* h0f   = wh16 + (size_t)G3 * HDIM;           // B*H
    unsigned short* h1f   = h0f + (size_t)B * HDIM;             // B*H
    unsigned short* hout  = h1f + (size_t)B * HDIM;             // B*H
    int*   rank = (int*)(hout + (size_t)B * HDIM);              // B
    unsigned int* sync = (unsigned int*)(rank + B);             // SYNC_TOTAL

    emb_kernel<<<B * S, 256, 0, stream>>>(seq, Ew, emb16);
    init_kernel<<<128, 256, 0, stream>>>(len, Wi, Wh, rank, sync,
                                         (unsigned int*)h0f, wi16, wh16);
    gi_gemm16<<<dim3(B * S / 64, G3 / 64), 256, 0, stream>>>(wi16, emb16, bi, gi16);

    gru_persist<<<dim3(NG, NJ), 256, 0, stream>>>(gi16, wh16, bh, len,
                                                  h0f, h1f, hout, sync);
    final_kernel<<<B, LDIM, 0, stream>>>(hout, Wl, bl, rank, out);
}

// Round 13
// 323.210 us; speedup vs baseline: 1.0536x; 1.0536x over previous
//
#include <hip/hip_runtime.h>
#include <cmath>

typedef _Float16 f16;
typedef _Float16 f16x8 __attribute__((ext_vector_type(8)));
typedef float f32x4 __attribute__((ext_vector_type(4)));
typedef unsigned int u32x4 __attribute__((ext_vector_type(4)));

#define B 64
#define S 80
#define KC 32
#define EDIM 256
#define HDIM 512
#define G3 1536
#define LDIM 128

// persistent-GRU geometry: 8 groups x 16 blocks x 32 cols, weights in LDS
#define NG 8     // groups (grid(8,16): linear%8 == g -> one XCD per group)
#define PG 8     // patients per group
#define NJ 16    // blocks per group (fan-in 16)
#define CPB 32   // h-cols per block

// sync area layout (u32 units)
#define OFF_PCNT  (NG * NJ * 64)
#define OFF_XCD   (OFF_PCNT + NG * 64)
#define OFF_TEST  (OFF_XCD + NG * NJ)
#define OFF_FAIL  (OFF_TEST + NG * NJ * 64)
#define SYNC_TOTAL (OFF_FAIL + NG)

// ---------------------------------------------------------------------------
__device__ __forceinline__ unsigned int ld_u32c(const unsigned int* p, bool l2) {
    unsigned int v;
    if (l2) {
        asm volatile("global_load_dword %0, %1, off sc0\n\ts_waitcnt vmcnt(0)"
                     : "=v"(v) : "v"(p) : "memory");
    } else {
        v = __hip_atomic_load(p, __ATOMIC_RELAXED, __HIP_MEMORY_SCOPE_AGENT);
    }
    return v;
}
__device__ __forceinline__ void st_u32c(unsigned int* p, unsigned int v, bool l2) {
    if (l2) {
        asm volatile("global_store_dword %0, %1, off sc0" :: "v"(p), "v"(v) : "memory");
    } else {
        __hip_atomic_store(p, v, __ATOMIC_RELAXED, __HIP_MEMORY_SCOPE_AGENT);
    }
}

// ---------------------------------------------------------------------------
// K1: multi-hot embedding + tanh -> f16.
__global__ __launch_bounds__(256) void emb_kernel(const int* __restrict__ seq,
                                                  const float* __restrict__ Ew,
                                                  unsigned short* __restrict__ emb16) {
    int bs = blockIdx.x;
    __shared__ int codes[KC];
    __shared__ int valid[KC];
    int tid = threadIdx.x;
    if (tid < KC) codes[tid] = seq[bs * KC + tid];
    __syncthreads();
    if (tid < KC) {
        int c = codes[tid];
        int v = (c != 0);
        for (int i = 0; i < tid; ++i)
            if (codes[i] == c) v = 0;
        valid[tid] = v;
    }
    __syncthreads();
    float acc = 0.f;
    for (int j = 0; j < KC; ++j) {
        if (valid[j]) acc += Ew[codes[j] * EDIM + tid];
    }
    emb16[bs * EDIM + tid] = __builtin_bit_cast(unsigned short, (f16)tanhf(acc));
}

// ---------------------------------------------------------------------------
// K2: Gi16 = emb16 @ Wi16^T + bi via MFMA f16 (verified).
__global__ __launch_bounds__(256) void gi_gemm16(
        const unsigned short* __restrict__ wi16,
        const unsigned short* __restrict__ emb16,
        const float* __restrict__ bi,
        unsigned short* __restrict__ gi16) {
    __shared__ __align__(16) f16 At[64][256];
    __shared__ __align__(16) f16 Bt[64][256];
    const int m0 = blockIdx.x * 64;   // visits
    const int n0 = blockIdx.y * 64;   // gates
    const int tid = threadIdx.x;
    #pragma unroll
    for (int i = 0; i < 8; ++i) {
        int ci = tid + i * 256;
        int row = ci >> 5, c = ci & 31;
        int sc = c ^ (row & 7);
        *(f32x4*)&At[row][sc * 8] =
            *(const f32x4*)(wi16 + (size_t)(n0 + row) * EDIM + c * 8);
        *(f32x4*)&Bt[row][sc * 8] =
            *(const f32x4*)(emb16 + (size_t)(m0 + row) * EDIM + c * 8);
    }
    __syncthreads();
    const int wv = tid >> 6, ln = tid & 63;
    const int lr = ln & 15, hi = ln >> 4;
    const int arow = wv * 16 + lr;
    f32x4 acc[4] = {};
    #pragma unroll
    for (int ks = 0; ks < 8; ++ks) {
        int ca = (ks * 4 + hi) ^ (arow & 7);
        f32x4 av = *(const f32x4*)&At[arow][ca * 8];
        #pragma unroll
        for (int vt = 0; vt < 4; ++vt) {
            int brow = vt * 16 + lr;
            int cb = (ks * 4 + hi) ^ (brow & 7);
            f32x4 bv = *(const f32x4*)&Bt[brow][cb * 8];
            acc[vt] = __builtin_amdgcn_mfma_f32_16x16x32_f16(
                __builtin_bit_cast(f16x8, av), __builtin_bit_cast(f16x8, bv),
                acc[vt], 0, 0, 0);
        }
    }
    const int gate0 = n0 + wv * 16 + hi * 4;
    float4 bv4 = *(const float4*)(bi + gate0);
    #pragma unroll
    for (int vt = 0; vt < 4; ++vt) {
        int vis = m0 + vt * 16 + lr;
        union { unsigned short u[4]; unsigned long long ll; } pk;
        pk.u[0] = __builtin_bit_cast(unsigned short, (f16)(acc[vt][0] + bv4.x));
        pk.u[1] = __builtin_bit_cast(unsigned short, (f16)(acc[vt][1] + bv4.y));
        pk.u[2] = __builtin_bit_cast(unsigned short, (f16)(acc[vt][2] + bv4.z));
        pk.u[3] = __builtin_bit_cast(unsigned short, (f16)(acc[vt][3] + bv4.w));
        *(unsigned long long*)(gi16 + (size_t)vis * G3 + gate0) = pk.ll;
    }
}

// ---------------------------------------------------------------------------
// K3: init — zero h buffers + sync, convert Wi/Wh -> f16, rank.
__global__ __launch_bounds__(256) void init_kernel(const int* __restrict__ len,
                                                   const float* __restrict__ Wi,
                                                   const float* __restrict__ Wh,
                                                   int* __restrict__ rank,
                                                   unsigned int* __restrict__ sync,
                                                   unsigned int* __restrict__ hz,
                                                   unsigned short* __restrict__ wi16,
                                                   unsigned short* __restrict__ wh16) {
    int idx = blockIdx.x * 256 + threadIdx.x;       // 128*256 = 32768
    if (idx < 16384) { hz[idx] = 0u; hz[16384 + idx] = 0u; }   // h0f+h1f
    for (int o = idx; o < SYNC_TOTAL; o += 32768) sync[o] = 0u;
    for (int o = idx; o < G3 * EDIM; o += 32768)
        wi16[o] = __builtin_bit_cast(unsigned short, (f16)Wi[o]);
    for (int o = idx; o < G3 * HDIM; o += 32768)
        wh16[o] = __builtin_bit_cast(unsigned short, (f16)Wh[o]);
    if (blockIdx.x == 0 && threadIdx.x < B) {
        int t = threadIdx.x;
        int lb = len[t];
        int r = 0;
        for (int i = 0; i < B; ++i) {
            int li = len[i];
            r += (li > lb) || (li == lb && i < t);
        }
        rank[t] = r;
    }
}

// ---------------------------------------------------------------------------
// K4: persistent MFMA GRU.  grid(8,16): block = 32 cols x 8 patients.
// Wh slice (96 rows x 512 k = 98 KB f16) staged ONCE into padded LDS
// [96][65] 16B-slots; per-step A-operands come from ds_read_b128 -- no L2
// weight traffic, no VGPR-residency fight (R3-R12 lesson: the allocator
// always remats big weight arrays).  Wave wv<3 computes gate wv for the
// block's 32 cols (2 MFMA col-tiles, 2x8 split-K chains).  Gates: thread
// (pat, 2 cols) -> one dword sc0 store (no LDS staging barrier).  Fan-in 16
// flag barrier; sc0/XCD-L2 when probed, L3 relaxed-agent fallback.
__global__ __launch_bounds__(256, 1) void gru_persist(
        const unsigned short* __restrict__ gi16,
        const unsigned short* __restrict__ wh16,
        const float* __restrict__ bh, const int* __restrict__ len,
        unsigned short* __restrict__ h0f, unsigned short* __restrict__ h1f,
        unsigned short* __restrict__ hout,
        unsigned int* __restrict__ sync) {
    const int g     = blockIdx.x;          // 0..7 (XCD under %8 map)
    const int slice = blockIdx.y;          // 0..15
    const int tid   = threadIdx.x;
    const int wv    = tid >> 6;
    const int ln    = tid & 63;
    const int c0    = slice * CPB;

    __shared__ __align__(16) f32x4 wlds[96 * 65];  // 99,840 B weight slice
    __shared__ __align__(16) f16 hsb[64][16][8];   // 16 KB  [k8][pat(8+8z)][8]
    __shared__ float ghl[3][CPB][16];              // 6 KB   [gate][col][pat]
    __shared__ unsigned int ids_sh[NJ];
    __shared__ unsigned int fail_sh;

    // zero pad-patient rows once (stay zero)
    for (int c = tid; c < 64 * 8; c += 256)
        *(float4*)&hsb[c >> 3][8 + (c & 7)][0] = make_float4(0.f, 0.f, 0.f, 0.f);

    // ---- stage Wh slice into LDS (96 rows x 64 slots, 24 iters)
    #pragma unroll
    for (int i = 0; i < 24; ++i) {
        int idx = tid + i * 256;           // 0..6143
        int row = idx >> 6, slot = idx & 63;
        int gate = row >> 5, lr = row & 31;
        wlds[row * 65 + slot] =
            *(const f32x4*)(wh16 + (size_t)(gate * HDIM + c0 + lr) * HDIM + slot * 8);
    }

    // ---- sync pointers
    unsigned int* gflags = sync + (size_t)(g * NJ) * 64;
    unsigned int* pcnt   = sync + OFF_PCNT + g * 64;
    unsigned int* xcdrow = sync + OFF_XCD + g * NJ;
    unsigned int* town   = sync + OFF_TEST + (g * NJ + slice) * 64;
    unsigned int* tpeer  = sync + OFF_TEST + (g * NJ + ((slice + 1) & (NJ - 1))) * 64;
    unsigned int* failw  = sync + OFF_FAIL + g;

    auto l3bar = [&](unsigned int target) {
        if (tid == 0) {
            asm volatile("s_waitcnt vmcnt(0)" ::: "memory");
            __hip_atomic_fetch_add(pcnt, 1u, __ATOMIC_RELAXED, __HIP_MEMORY_SCOPE_AGENT);
            while (__hip_atomic_load(pcnt, __ATOMIC_RELAXED, __HIP_MEMORY_SCOPE_AGENT) < target)
                __builtin_amdgcn_s_sleep(1);
        }
        __syncthreads();
    };

    // ---- XCD identity + sc0 coherence probe (R6 recipe, proven)
    unsigned int myxcc;
    asm volatile("s_getreg_b32 %0, hwreg(HW_REG_XCC_ID)" : "=s"(myxcc));
    myxcc &= 0xFu;
    if (tid == 0)
        __hip_atomic_store(xcdrow + slice, myxcc, __ATOMIC_RELAXED, __HIP_MEMORY_SCOPE_AGENT);
    l3bar(NJ);
    if (tid < NJ)
        ids_sh[tid] = __hip_atomic_load(xcdrow + tid, __ATOMIC_RELAXED, __HIP_MEMORY_SCOPE_AGENT);
    __syncthreads();
    bool same_xcd = true;
    #pragma unroll
    for (int i = 1; i < NJ; ++i) same_xcd &= (ids_sh[i] == ids_sh[0]);

    bool l2m = false;
    if (same_xcd) {
        const unsigned int M1 = 0xA5A50000u + (unsigned)slice;
        const unsigned int M2 = 0x5A5A0000u + (unsigned)slice;
        const unsigned int P1 = 0xA5A50000u + (unsigned)((slice + 1) & (NJ - 1));
        const unsigned int P2 = 0x5A5A0000u + (unsigned)((slice + 1) & (NJ - 1));
        unsigned int r1 = 0, r2 = 0;
        if (tid == 0) st_u32c(town, M1, true);
        l3bar(2 * NJ);
        if (tid == 0) r1 = ld_u32c(tpeer, true);
        l3bar(3 * NJ);
        if (tid == 0) st_u32c(town, M2, true);
        l3bar(4 * NJ);
        if (tid == 0) {
            r2 = ld_u32c(tpeer, true);
            if (r1 != P1 || r2 != P2)
                __hip_atomic_fetch_or(failw, 1u, __ATOMIC_RELAXED, __HIP_MEMORY_SCOPE_AGENT);
        }
        l3bar(5 * NJ);
        if (tid == 0)
            fail_sh = __hip_atomic_load(failw, __ATOMIC_RELAXED, __HIP_MEMORY_SCOPE_AGENT);
        __syncthreads();
        l2m = (fail_sh == 0u);
    }

    // ---- per-thread statics (tid<128: pat = tid>>4, 2 cols = (tid&15)*2)
    const int pat  = tid >> 4;             // valid for tid<128: 0..7
    const int cp   = tid & 15;
    const int colw = cp * 2;               // col within block (pair base)
    const int colg = c0 + colw;
    const int fb   = g * PG + pat;
    float2 bhp[3] = {};
    const unsigned short* gi_b = gi16;
    int flen = 0;
    if (tid < 128) {
        #pragma unroll
        for (int gg = 0; gg < 3; ++gg)
            bhp[gg] = *(const float2*)(bh + gg * HDIM + colg);
        gi_b = gi16 + (size_t)fb * S * G3;
        flen = len[fb];
    }
    int Lg = 0;
    #pragma unroll
    for (int i = 0; i < PG; ++i) Lg = max(Lg, len[g * PG + i]);

    unsigned short* hb0 = h0f + (size_t)g * PG * HDIM;
    unsigned short* hb1 = h1f + (size_t)g * PG * HDIM;

    // gather chunks: c = tid, tid+256 -> pat = c&7, k8 = c>>3
    const int g0p = tid & 7, g0k = tid >> 3;
    const int g1k = g0k + 32;

    // ---- Gi(0) prologue prefetch (3 dwords = 3 x f16x2)
    unsigned int giC[3] = {};
    if (tid < 128) {
        #pragma unroll
        for (int gg = 0; gg < 3; ++gg)
            giC[gg] = *(const unsigned int*)(gi_b + gg * HDIM + colg);
    }

    unsigned int lastH = 0;   // packed 2 f16

    #pragma unroll 1
    for (int t = 0; t < Lg; ++t) {
        const unsigned short* src = (t & 1) ? hb1 : hb0;
        unsigned short*       dst = (t & 1) ? hb0 : hb1;

        // ---- gather h_t (8 pats x 512) into LDS
        {
            const unsigned short* p0 = src + g0p * HDIM + g0k * 8;
            const unsigned short* p1 = src + g0p * HDIM + g1k * 8;
            if (l2m) {
                u32x4 v0, v1;
                asm volatile(
                    "global_load_dwordx4 %0, %2, off sc0\n\t"
                    "global_load_dwordx4 %1, %3, off sc0\n\t"
                    "s_waitcnt vmcnt(0)"
                    : "=v"(v0), "=v"(v1) : "v"(p0), "v"(p1) : "memory");
                *(u32x4*)&hsb[g0k][g0p][0] = v0;
                *(u32x4*)&hsb[g1k][g0p][0] = v1;
            } else {
                u32x4 v0, v1;
                #pragma unroll
                for (int i = 0; i < 4; ++i) {
                    v0[i] = __hip_atomic_load((const unsigned int*)p0 + i,
                                              __ATOMIC_RELAXED, __HIP_MEMORY_SCOPE_AGENT);
                    v1[i] = __hip_atomic_load((const unsigned int*)p1 + i,
                                              __ATOMIC_RELAXED, __HIP_MEMORY_SCOPE_AGENT);
                }
                *(u32x4*)&hsb[g0k][g0p][0] = v0;
                *(u32x4*)&hsb[g1k][g0p][0] = v1;
            }
        }
        __syncthreads();

        // ---- MFMA: wave wv = gate wv; 2 col-tiles x (2x8 K-chains)
        if (wv < 3) {
            const int lr = ln & 15, hi = ln >> 4;
            #pragma unroll
            for (int cc = 0; cc < 2; ++cc) {
                const f32x4* wrow = &wlds[(wv * 32 + cc * 16 + lr) * 65 + hi];
                f32x4 a0 = (f32x4){0.f, 0.f, 0.f, 0.f};
                f32x4 a1 = (f32x4){0.f, 0.f, 0.f, 0.f};
                #pragma unroll
                for (int ks = 0; ks < 8; ++ks) {
                    f32x4 av = wrow[ks * 4];
                    f32x4 bv = *(const f32x4*)&hsb[ks * 4 + hi][lr][0];
                    a0 = __builtin_amdgcn_mfma_f32_16x16x32_f16(
                        __builtin_bit_cast(f16x8, av),
                        __builtin_bit_cast(f16x8, bv), a0, 0, 0, 0);
                }
                #pragma unroll
                for (int ks = 8; ks < 16; ++ks) {
                    f32x4 av = wrow[ks * 4];
                    f32x4 bv = *(const f32x4*)&hsb[ks * 4 + hi][lr][0];
                    a1 = __builtin_amdgcn_mfma_f32_16x16x32_f16(
                        __builtin_bit_cast(f16x8, av),
                        __builtin_bit_cast(f16x8, bv), a1, 0, 0, 0);
                }
                #pragma unroll
                for (int i = 0; i < 4; ++i)
                    ghl[wv][cc * 16 + hi * 4 + i][lr] = a0[i] + a1[i];
            }
        }
        __syncthreads();

        // ---- gates: thread owns (pat, 2 cols); direct dword sc0 store
        if (tid < 128) {
            unsigned int hold2 =
                *(const unsigned int*)&hsb[colg >> 3][pat][colg & 7];
            union { f16 h[2]; unsigned int v; } pk, hv;
            hv.v = hold2;
            #pragma unroll
            for (int i = 0; i < 2; ++i) {
                float sr = ghl[0][colw + i][pat];
                float sz = ghl[1][colw + i][pat];
                float sn = ghl[2][colw + i][pat];
                f16 g2[2];
                *(unsigned int*)g2 = giC[0];
                float gr = (float)g2[i];
                *(unsigned int*)g2 = giC[1];
                float gz = (float)g2[i];
                *(unsigned int*)g2 = giC[2];
                float gn = (float)g2[i];
                float bb = i ? bhp[0].y : bhp[0].x;
                float bz = i ? bhp[1].y : bhp[1].x;
                float bn = i ? bhp[2].y : bhp[2].x;
                float r  = 1.f / (1.f + expf(-(gr + sr + bb)));
                float z  = 1.f / (1.f + expf(-(gz + sz + bz)));
                float nn = tanhf(gn + r * (sn + bn));
                float hold = (float)hv.h[i];
                float hnew = (t < flen) ? ((1.f - z) * nn + z * hold) : hold;
                pk.h[i] = (f16)hnew;
            }
            lastH = pk.v;
            unsigned short* d = dst + pat * HDIM + colg;
            if (l2m) {
                asm volatile("global_store_dword %0, %1, off sc0"
                             :: "v"(d), "v"(pk.v) : "memory");
            } else {
                __hip_atomic_store((unsigned int*)d, pk.v,
                                   __ATOMIC_RELAXED, __HIP_MEMORY_SCOPE_AGENT);
            }
        }
        // each wave drains its own stores before the barrier; then flag
        asm volatile("s_waitcnt vmcnt(0)" ::: "memory");
        __syncthreads();
        if (tid == 0) st_u32c(gflags + slice * 64, (unsigned)(t + 1), l2m);

        // ---- Gi(t+1) prefetch AFTER flag publish (overlaps the poll)
        unsigned int giN[3] = {};
        if (tid < 128) {
            int tn = (t + 1 < S) ? (t + 1) : (S - 1);
            const unsigned short* gp = gi_b + (size_t)tn * G3;
            #pragma unroll
            for (int gg = 0; gg < 3; ++gg)
                giN[gg] = *(const unsigned int*)(gp + gg * HDIM + colg);
        }

        // ---- parallel poll for all 16 peers at step t+1
        if (tid < NJ) {
            unsigned int* f = gflags + tid * 64;
            while (ld_u32c(f, l2m) < (unsigned)(t + 1))
                __builtin_amdgcn_s_sleep(1);
        }
        __syncthreads();

        giC[0] = giN[0]; giC[1] = giN[1]; giC[2] = giN[2];
    }

    // ---- final h -> hout (thread owns (pat, 2 cols))
    if (tid < 128)
        *(unsigned int*)(hout + (size_t)fb * HDIM + colg) = lastH;
}

// ---------------------------------------------------------------------------
// K5: out[rank[b]] = tanh(W_lat @ h[b] + b_lat), h f16.
__global__ __launch_bounds__(128) void final_kernel(const unsigned short* __restrict__ h,
                                                    const float* __restrict__ Wl,
                                                    const float* __restrict__ bl,
                                                    const int* __restrict__ rank,
                                                    float* __restrict__ out) {
    int b = blockIdx.x;
    int l = threadIdx.x;
    __shared__ float hsh[HDIM];
    for (int i = l; i < HDIM; i += LDIM)
        hsh[i] = (float)__builtin_bit_cast(f16, h[(size_t)b * HDIM + i]);
    __syncthreads();
    float acc = bl[l];
    for (int k = 0; k < HDIM; ++k) acc += hsh[k] * Wl[(size_t)l * HDIM + k];
    out[(size_t)rank[b] * LDIM + l] = tanhf(acc);
}

// ---------------------------------------------------------------------------
extern "C" void kernel_launch(void* const* d_in, const int* in_sizes, int n_in,
                              void* d_out, int out_size, void* d_ws, size_t ws_size,
                              hipStream_t stream) {
    const int*   seq = (const int*)d_in[0];
    const int*   len = (const int*)d_in[1];
    const float* Ew  = (const float*)d_in[2];
    const float* Wi  = (const float*)d_in[3];
    const float* Wh  = (const float*)d_in[4];
    const float* bi  = (const float*)d_in[5];
    const float* bh  = (const float*)d_in[6];
    const float* Wl  = (const float*)d_in[7];
    const float* bl  = (const float*)d_in[8];
    float* out = (float*)d_out;

    unsigned short* ws16 = (unsigned short*)d_ws;
    unsigned short* emb16 = ws16;                               // B*S*E
    unsigned short* gi16  = emb16 + (size_t)B * S * EDIM;       // B*S*3H
    unsigned short* wi16  = gi16 + (size_t)B * S * G3;          // 3H*E
    unsigned short* wh16  = wi16 + (size_t)G3 * EDIM;           // 3H*H
    unsigned short* h0f   = wh16 + (size_t)G3 * HDIM;           // B*H
    unsigned short* h1f   = h0f + (size_t)B * HDIM;             // B*H
    unsigned short* hout  = h1f + (size_t)B * HDIM;             // B*H
    int*   rank = (int*)(hout + (size_t)B * HDIM);              // B
    unsigned int* sync = (unsigned int*)(rank + B);             // SYNC_TOTAL

    emb_kernel<<<B * S, 256, 0, stream>>>(seq, Ew, emb16);
    init_kernel<<<128, 256, 0, stream>>>(len, Wi, Wh, rank, sync,
                                         (unsigned int*)h0f, wi16, wh16);
    gi_gemm16<<<dim3(B * S / 64, G3 / 64), 256, 0, stream>>>(wi16, emb16, bi, gi16);

    gru_persist<<<dim3(NG, NJ), 256, 0, stream>>>(gi16, wh16, bh, len,
                                                  h0f, h1f, hout, sync);
    final_kernel<<<B, LDIM, 0, stream>>>(hout, Wl, bl, rank, out);
}

// Round 14
// 308.075 us; speedup vs baseline: 1.1054x; 1.0491x over previous
//
#include <hip/hip_runtime.h>
#include <cmath>

typedef _Float16 f16;
typedef _Float16 f16x8 __attribute__((ext_vector_type(8)));
typedef float f32x4 __attribute__((ext_vector_type(4)));
typedef unsigned int u32x4 __attribute__((ext_vector_type(4)));

#define B 64
#define S 80
#define KC 32
#define EDIM 256
#define HDIM 512
#define G3 1536
#define LDIM 128

// persistent-GRU geometry (R11 core)
#define NG 8     // groups (grid(8,32): linear%8 == g -> one XCD per group)
#define PG 8     // patients per group
#define NJ 32    // blocks per group
#define CPB 16   // h-cols per block

// sync area layout (u32 units)
#define OFF_PCNT  (NG * NJ * 64)
#define OFF_XCD   (OFF_PCNT + NG * 64)
#define OFF_TEST  (OFF_XCD + NG * NJ)
#define OFF_FAIL  (OFF_TEST + NG * NJ * 64)
#define SYNC_TOTAL (OFF_FAIL + NG)

// ---------------------------------------------------------------------------
__device__ __forceinline__ unsigned int ld_u32c(const unsigned int* p, bool l2) {
    unsigned int v;
    if (l2) {
        asm volatile("global_load_dword %0, %1, off sc0\n\ts_waitcnt vmcnt(0)"
                     : "=v"(v) : "v"(p) : "memory");
    } else {
        v = __hip_atomic_load(p, __ATOMIC_RELAXED, __HIP_MEMORY_SCOPE_AGENT);
    }
    return v;
}
__device__ __forceinline__ void st_u32c(unsigned int* p, unsigned int v, bool l2) {
    if (l2) {
        asm volatile("global_store_dword %0, %1, off sc0" :: "v"(p), "v"(v) : "memory");
    } else {
        __hip_atomic_store(p, v, __ATOMIC_RELAXED, __HIP_MEMORY_SCOPE_AGENT);
    }
}

// ---------------------------------------------------------------------------
// K1: multi-hot embedding + tanh -> f16.
__global__ __launch_bounds__(256) void emb_kernel(const int* __restrict__ seq,
                                                  const float* __restrict__ Ew,
                                                  unsigned short* __restrict__ emb16) {
    int bs = blockIdx.x;
    __shared__ int codes[KC];
    __shared__ int valid[KC];
    int tid = threadIdx.x;
    if (tid < KC) codes[tid] = seq[bs * KC + tid];
    __syncthreads();
    if (tid < KC) {
        int c = codes[tid];
        int v = (c != 0);
        for (int i = 0; i < tid; ++i)
            if (codes[i] == c) v = 0;
        valid[tid] = v;
    }
    __syncthreads();
    float acc = 0.f;
    for (int j = 0; j < KC; ++j) {
        if (valid[j]) acc += Ew[codes[j] * EDIM + tid];
    }
    emb16[bs * EDIM + tid] = __builtin_bit_cast(unsigned short, (f16)tanhf(acc));
}

// ---------------------------------------------------------------------------
// K2: Gi16 = emb16 @ Wi16^T + bi via MFMA f16 (verified).
__global__ __launch_bounds__(256) void gi_gemm16(
        const unsigned short* __restrict__ wi16,
        const unsigned short* __restrict__ emb16,
        const float* __restrict__ bi,
        unsigned short* __restrict__ gi16) {
    __shared__ __align__(16) f16 At[64][256];
    __shared__ __align__(16) f16 Bt[64][256];
    const int m0 = blockIdx.x * 64;   // visits
    const int n0 = blockIdx.y * 64;   // gates
    const int tid = threadIdx.x;
    #pragma unroll
    for (int i = 0; i < 8; ++i) {
        int ci = tid + i * 256;
        int row = ci >> 5, c = ci & 31;
        int sc = c ^ (row & 7);
        *(f32x4*)&At[row][sc * 8] =
            *(const f32x4*)(wi16 + (size_t)(n0 + row) * EDIM + c * 8);
        *(f32x4*)&Bt[row][sc * 8] =
            *(const f32x4*)(emb16 + (size_t)(m0 + row) * EDIM + c * 8);
    }
    __syncthreads();
    const int wv = tid >> 6, ln = tid & 63;
    const int lr = ln & 15, hi = ln >> 4;
    const int arow = wv * 16 + lr;
    f32x4 acc[4] = {};
    #pragma unroll
    for (int ks = 0; ks < 8; ++ks) {
        int ca = (ks * 4 + hi) ^ (arow & 7);
        f32x4 av = *(const f32x4*)&At[arow][ca * 8];
        #pragma unroll
        for (int vt = 0; vt < 4; ++vt) {
            int brow = vt * 16 + lr;
            int cb = (ks * 4 + hi) ^ (brow & 7);
            f32x4 bv = *(const f32x4*)&Bt[brow][cb * 8];
            acc[vt] = __builtin_amdgcn_mfma_f32_16x16x32_f16(
                __builtin_bit_cast(f16x8, av), __builtin_bit_cast(f16x8, bv),
                acc[vt], 0, 0, 0);
        }
    }
    const int gate0 = n0 + wv * 16 + hi * 4;
    float4 bv4 = *(const float4*)(bi + gate0);
    #pragma unroll
    for (int vt = 0; vt < 4; ++vt) {
        int vis = m0 + vt * 16 + lr;
        union { unsigned short u[4]; unsigned long long ll; } pk;
        pk.u[0] = __builtin_bit_cast(unsigned short, (f16)(acc[vt][0] + bv4.x));
        pk.u[1] = __builtin_bit_cast(unsigned short, (f16)(acc[vt][1] + bv4.y));
        pk.u[2] = __builtin_bit_cast(unsigned short, (f16)(acc[vt][2] + bv4.z));
        pk.u[3] = __builtin_bit_cast(unsigned short, (f16)(acc[vt][3] + bv4.w));
        *(unsigned long long*)(gi16 + (size_t)vis * G3 + gate0) = pk.ll;
    }
}

// ---------------------------------------------------------------------------
// K3: init — zero h buffers + sync, convert Wi/Wh -> f16, rank.
__global__ __launch_bounds__(256) void init_kernel(const int* __restrict__ len,
                                                   const float* __restrict__ Wi,
                                                   const float* __restrict__ Wh,
                                                   int* __restrict__ rank,
                                                   unsigned int* __restrict__ sync,
                                                   unsigned int* __restrict__ hz,
                                                   unsigned short* __restrict__ wi16,
                                                   unsigned short* __restrict__ wh16) {
    int idx = blockIdx.x * 256 + threadIdx.x;       // 128*256 = 32768
    if (idx < 16384) { hz[idx] = 0u; hz[16384 + idx] = 0u; }   // h0f+h1f
    for (int o = idx; o < SYNC_TOTAL; o += 32768) sync[o] = 0u;
    for (int o = idx; o < G3 * EDIM; o += 32768)
        wi16[o] = __builtin_bit_cast(unsigned short, (f16)Wi[o]);
    for (int o = idx; o < G3 * HDIM; o += 32768)
        wh16[o] = __builtin_bit_cast(unsigned short, (f16)Wh[o]);
    if (blockIdx.x == 0 && threadIdx.x < B) {
        int t = threadIdx.x;
        int lb = len[t];
        int r = 0;
        for (int i = 0; i < B; ++i) {
            int li = len[i];
            r += (li > lb) || (li == lb && i < t);
        }
        rank[t] = r;
    }
}

// ---------------------------------------------------------------------------
// K4: persistent MFMA GRU — R11 core (205us) with the step TAIL collapsed
// into wave 0: lanes 0..63 own (pat, 2 cols) -> gates + one dword store +
// WAVE-LOCAL vmcnt drain + flag, while wave 1 polls peers concurrently.
// 3 barriers/step (was 4), no hst staging pass, store-drain off the
// all-wave path.  Gi(t+1) issued after the flag into dead giC regs; its
// drain folds into B3 (overlaps the poll).  sc0/XCD-L2 when probed OK,
// L3 relaxed-agent fallback.
__global__ __launch_bounds__(256, 1) void gru_persist(
        const unsigned short* __restrict__ gi16,
        const unsigned short* __restrict__ wh16,
        const float* __restrict__ bh, const int* __restrict__ len,
        unsigned short* __restrict__ h0f, unsigned short* __restrict__ h1f,
        unsigned short* __restrict__ hout,
        unsigned int* __restrict__ sync) {
    const int g     = blockIdx.x;          // 0..NG-1
    const int slice = blockIdx.y;          // 0..NJ-1
    const int tid   = threadIdx.x;
    const int wv    = tid >> 6;
    const int ln    = tid & 63;
    const int c0    = slice * CPB;

    __shared__ __align__(16) f16 hsb[64][16][8];   // [k8][pat(8+8 pad)][8]
    __shared__ float ghl[3][16][18];               // [gate][col][pat] pad 18
    __shared__ unsigned int ids_sh[NJ];
    __shared__ unsigned int fail_sh;

    // zero pad-patient rows once (stay zero)
    for (int c = tid; c < 64 * 8; c += 256)
        *(float4*)&hsb[c >> 3][8 + (c & 7)][0] = make_float4(0.f, 0.f, 0.f, 0.f);

    // ---- A-operand (Wh f16 slice) per wave (wv<3)
    f32x4 af[16];
    if (wv < 3) {
        const unsigned short* wrow =
            wh16 + (size_t)(wv * HDIM + c0 + (ln & 15)) * HDIM + (ln >> 4) * 8;
        #pragma unroll
        for (int ks = 0; ks < 16; ++ks)
            af[ks] = *(const f32x4*)(wrow + ks * 32);
    } else {
        #pragma unroll
        for (int ks = 0; ks < 16; ++ks) af[ks] = (f32x4){0.f, 0.f, 0.f, 0.f};
    }
    #pragma unroll
    for (int ks = 0; ks < 16; ++ks) asm volatile("" : "+v"(af[ks]));

    // ---- sync pointers
    unsigned int* gflags = sync + (size_t)(g * NJ) * 64;
    unsigned int* pcnt   = sync + OFF_PCNT + g * 64;
    unsigned int* xcdrow = sync + OFF_XCD + g * NJ;
    unsigned int* town   = sync + OFF_TEST + (g * NJ + slice) * 64;
    unsigned int* tpeer  = sync + OFF_TEST + (g * NJ + ((slice + 1) & (NJ - 1))) * 64;
    unsigned int* failw  = sync + OFF_FAIL + g;

    auto l3bar = [&](unsigned int target) {
        if (tid == 0) {
            asm volatile("s_waitcnt vmcnt(0)" ::: "memory");
            __hip_atomic_fetch_add(pcnt, 1u, __ATOMIC_RELAXED, __HIP_MEMORY_SCOPE_AGENT);
            while (__hip_atomic_load(pcnt, __ATOMIC_RELAXED, __HIP_MEMORY_SCOPE_AGENT) < target)
                __builtin_amdgcn_s_sleep(1);
        }
        __syncthreads();
    };

    // ---- XCD identity + sc0 coherence probe (R6 recipe, proven)
    unsigned int myxcc;
    asm volatile("s_getreg_b32 %0, hwreg(HW_REG_XCC_ID)" : "=s"(myxcc));
    myxcc &= 0xFu;
    if (tid == 0)
        __hip_atomic_store(xcdrow + slice, myxcc, __ATOMIC_RELAXED, __HIP_MEMORY_SCOPE_AGENT);
    l3bar(NJ);
    if (tid < NJ)
        ids_sh[tid] = __hip_atomic_load(xcdrow + tid, __ATOMIC_RELAXED, __HIP_MEMORY_SCOPE_AGENT);
    __syncthreads();
    bool same_xcd = true;
    #pragma unroll
    for (int i = 1; i < NJ; ++i) same_xcd &= (ids_sh[i] == ids_sh[0]);

    bool l2m = false;
    if (same_xcd) {
        const unsigned int M1 = 0xA5A50000u + (unsigned)slice;
        const unsigned int M2 = 0x5A5A0000u + (unsigned)slice;
        const unsigned int P1 = 0xA5A50000u + (unsigned)((slice + 1) & (NJ - 1));
        const unsigned int P2 = 0x5A5A0000u + (unsigned)((slice + 1) & (NJ - 1));
        unsigned int r1 = 0, r2 = 0;
        if (tid == 0) st_u32c(town, M1, true);
        l3bar(2 * NJ);
        if (tid == 0) r1 = ld_u32c(tpeer, true);
        l3bar(3 * NJ);
        if (tid == 0) st_u32c(town, M2, true);
        l3bar(4 * NJ);
        if (tid == 0) {
            r2 = ld_u32c(tpeer, true);
            if (r1 != P1 || r2 != P2)
                __hip_atomic_fetch_or(failw, 1u, __ATOMIC_RELAXED, __HIP_MEMORY_SCOPE_AGENT);
        }
        l3bar(5 * NJ);
        if (tid == 0)
            fail_sh = __hip_atomic_load(failw, __ATOMIC_RELAXED, __HIP_MEMORY_SCOPE_AGENT);
        __syncthreads();
        l2m = (fail_sh == 0u);
    }

    // ---- per-lane statics for the tail (wave 0: tid<64)
    const int pat  = tid >> 3;             // 0..7   (valid for tid<64)
    const int colw = (tid & 7) * 2;        // 0..14
    const int colg = c0 + colw;
    const int fb   = g * PG + pat;
    float2 bhp[3] = {};
    const unsigned short* gi_b = gi16;
    int flen = 0;
    if (tid < 64) {
        #pragma unroll
        for (int gg = 0; gg < 3; ++gg)
            bhp[gg] = *(const float2*)(bh + gg * HDIM + colg);
        gi_b = gi16 + (size_t)fb * S * G3;
        flen = len[fb];
    }
    int Lg = 0;
    #pragma unroll
    for (int i = 0; i < PG; ++i) Lg = max(Lg, len[g * PG + i]);

    unsigned short* hb0 = h0f + (size_t)g * PG * HDIM;
    unsigned short* hb1 = h1f + (size_t)g * PG * HDIM;

    // gather chunks: c = tid, tid+256 -> pat = c&7, k8 = c>>3
    const int g0p = tid & 7, g0k = tid >> 3;
    const int g1k = g0k + 32;

    // ---- Gi(0) prologue prefetch (3 dwords = 3 f16-pairs)
    unsigned int giC[3] = {};
    if (tid < 64) {
        #pragma unroll
        for (int gg = 0; gg < 3; ++gg)
            giC[gg] = *(const unsigned int*)(gi_b + gg * HDIM + colg);
    }

    unsigned int lastH = 0;   // packed 2 f16

    #pragma unroll 1
    for (int t = 0; t < Lg; ++t) {
        const unsigned short* src = (t & 1) ? hb1 : hb0;
        unsigned short*       dst = (t & 1) ? hb0 : hb1;

        // ---- gather h_t (8 pats x 512) into LDS
        {
            const unsigned short* p0 = src + g0p * HDIM + g0k * 8;
            const unsigned short* p1 = src + g0p * HDIM + g1k * 8;
            if (l2m) {
                u32x4 v0, v1;
                asm volatile(
                    "global_load_dwordx4 %0, %2, off sc0\n\t"
                    "global_load_dwordx4 %1, %3, off sc0\n\t"
                    "s_waitcnt vmcnt(0)"
                    : "=v"(v0), "=v"(v1) : "v"(p0), "v"(p1) : "memory");
                *(u32x4*)&hsb[g0k][g0p][0] = v0;
                *(u32x4*)&hsb[g1k][g0p][0] = v1;
            } else {
                u32x4 v0, v1;
                #pragma unroll
                for (int i = 0; i < 4; ++i) {
                    v0[i] = __hip_atomic_load((const unsigned int*)p0 + i,
                                              __ATOMIC_RELAXED, __HIP_MEMORY_SCOPE_AGENT);
                    v1[i] = __hip_atomic_load((const unsigned int*)p1 + i,
                                              __ATOMIC_RELAXED, __HIP_MEMORY_SCOPE_AGENT);
                }
                *(u32x4*)&hsb[g0k][g0p][0] = v0;
                *(u32x4*)&hsb[g1k][g0p][0] = v1;
            }
        }
        __syncthreads();                                   // B1

        // ---- MFMA: wave wv = gate wv; 2x8 independent K-chains
        if (wv < 3) {
            f32x4 a0 = (f32x4){0.f, 0.f, 0.f, 0.f};
            f32x4 a1 = (f32x4){0.f, 0.f, 0.f, 0.f};
            #pragma unroll
            for (int ks = 0; ks < 8; ++ks) {
                f32x4 bv = *(const f32x4*)&hsb[ks * 4 + (ln >> 4)][ln & 15][0];
                a0 = __builtin_amdgcn_mfma_f32_16x16x32_f16(
                    __builtin_bit_cast(f16x8, af[ks]),
                    __builtin_bit_cast(f16x8, bv), a0, 0, 0, 0);
            }
            #pragma unroll
            for (int ks = 8; ks < 16; ++ks) {
                f32x4 bv = *(const f32x4*)&hsb[ks * 4 + (ln >> 4)][ln & 15][0];
                a1 = __builtin_amdgcn_mfma_f32_16x16x32_f16(
                    __builtin_bit_cast(f16x8, af[ks]),
                    __builtin_bit_cast(f16x8, bv), a1, 0, 0, 0);
            }
            #pragma unroll
            for (int i = 0; i < 4; ++i)
                ghl[wv][(ln >> 4) * 4 + i][ln & 15] = a0[i] + a1[i];
        }
        __syncthreads();                                   // B2

        // ---- tail: wave 0 gates+store+drain+flag+Gi ; wave 1 polls
        if (tid < 64) {
            unsigned int hold2 =
                *(const unsigned int*)&hsb[colg >> 3][pat][colg & 7];
            union { f16 h[2]; unsigned int v; } pk, hv, gp;
            hv.v = hold2;
            #pragma unroll
            for (int i = 0; i < 2; ++i) {
                float sr = ghl[0][colw + i][pat];
                float sz = ghl[1][colw + i][pat];
                float sn = ghl[2][colw + i][pat];
                gp.v = giC[0]; float gr = (float)gp.h[i];
                gp.v = giC[1]; float gz = (float)gp.h[i];
                gp.v = giC[2]; float gn = (float)gp.h[i];
                float bb = i ? bhp[0].y : bhp[0].x;
                float bz = i ? bhp[1].y : bhp[1].x;
                float bn = i ? bhp[2].y : bhp[2].x;
                float r  = 1.f / (1.f + expf(-(gr + sr + bb)));
                float z  = 1.f / (1.f + expf(-(gz + sz + bz)));
                float nn = tanhf(gn + r * (sn + bn));
                float hold = (float)hv.h[i];
                float hnew = (t < flen) ? ((1.f - z) * nn + z * hold) : hold;
                pk.h[i] = (f16)hnew;
            }
            lastH = pk.v;
            unsigned short* d = dst + pat * HDIM + colg;
            if (l2m) {
                asm volatile("global_store_dword %0, %1, off sc0"
                             :: "v"(d), "v"(pk.v) : "memory");
            } else {
                __hip_atomic_store((unsigned int*)d, pk.v,
                                   __ATOMIC_RELAXED, __HIP_MEMORY_SCOPE_AGENT);
            }
            // wave-0-local drain: all of wave 0's h stores at coherence point
            asm volatile("s_waitcnt vmcnt(0)" ::: "memory");
            if (tid == 0) st_u32c(gflags + slice * 64, (unsigned)(t + 1), l2m);
            // Gi(t+1) AFTER flag: giC is dead, load directly (drain at B3)
            int tn = (t + 1 < S) ? (t + 1) : (S - 1);
            const unsigned short* gpp = gi_b + (size_t)tn * G3;
            #pragma unroll
            for (int gg = 0; gg < 3; ++gg)
                giC[gg] = *(const unsigned int*)(gpp + gg * HDIM + colg);
        } else if (tid < 64 + NJ) {
            unsigned int* f = gflags + (tid - 64) * 64;
            while (ld_u32c(f, l2m) < (unsigned)(t + 1))
                __builtin_amdgcn_s_sleep(1);
        }
        __syncthreads();                                   // B3
    }

    // ---- final h -> hout (lane owns (pat, 2 cols))
    if (tid < 64)
        *(unsigned int*)(hout + (size_t)fb * HDIM + colg) = lastH;
}

// ---------------------------------------------------------------------------
// K5: out[rank[b]] = tanh(W_lat @ h[b] + b_lat), h f16.
__global__ __launch_bounds__(128) void final_kernel(const unsigned short* __restrict__ h,
                                                    const float* __restrict__ Wl,
                                                    const float* __restrict__ bl,
                                                    const int* __restrict__ rank,
                                                    float* __restrict__ out) {
    int b = blockIdx.x;
    int l = threadIdx.x;
    __shared__ float hsh[HDIM];
    for (int i = l; i < HDIM; i += LDIM)
        hsh[i] = (float)__builtin_bit_cast(f16, h[(size_t)b * HDIM + i]);
    __syncthreads();
    float acc = bl[l];
    for (int k = 0; k < HDIM; ++k) acc += hsh[k] * Wl[(size_t)l * HDIM + k];
    out[(size_t)rank[b] * LDIM + l] = tanhf(acc);
}

// ---------------------------------------------------------------------------
extern "C" void kernel_launch(void* const* d_in, const int* in_sizes, int n_in,
                              void* d_out, int out_size, void* d_ws, size_t ws_size,
                              hipStream_t stream) {
    const int*   seq = (const int*)d_in[0];
    const int*   len = (const int*)d_in[1];
    const float* Ew  = (const float*)d_in[2];
    const float* Wi  = (const float*)d_in[3];
    const float* Wh  = (const float*)d_in[4];
    const float* bi  = (const float*)d_in[5];
    const float* bh  = (const float*)d_in[6];
    const float* Wl  = (const float*)d_in[7];
    const float* bl  = (const float*)d_in[8];
    float* out = (float*)d_out;

    unsigned short* ws16 = (unsigned short*)d_ws;
    unsigned short* emb16 = ws16;                               // B*S*E
    unsigned short* gi16  = emb16 + (size_t)B * S * EDIM;       // B*S*3H
    unsigned short* wi16  = gi16 + (size_t)B * S * G3;          // 3H*E
    unsigned short* wh16  = wi16 + (size_t)G3 * EDIM;           // 3H*H
    unsigned short* h0f   = wh16 + (size_t)G3 * HDIM;           // B*H
    unsigned short* h1f   = h0f + (size_t)B * HDIM;             // B*H
    unsigned short* hout  = h1f + (size_t)B * HDIM;             // B*H
    int*   rank = (int*)(hout + (size_t)B * HDIM);              // B
    unsigned int* sync = (unsigned int*)(rank + B);             // SYNC_TOTAL

    emb_kernel<<<B * S, 256, 0, stream>>>(seq, Ew, emb16);
    init_kernel<<<128, 256, 0, stream>>>(len, Wi, Wh, rank, sync,
                                         (unsigned int*)h0f, wi16, wh16);
    gi_gemm16<<<dim3(B * S / 64, G3 / 64), 256, 0, stream>>>(wi16, emb16, bi, gi16);

    gru_persist<<<dim3(NG, NJ), 256, 0, stream>>>(gi16, wh16, bh, len,
                                                  h0f, h1f, hout, sync);
    final_kernel<<<B, LDIM, 0, stream>>>(hout, Wl, bl, rank, out);
}